// Round 9
// baseline (177.982 us; speedup 1.0000x reference)
//
#include <hip/hip_runtime.h>
#include <hip/hip_bf16.h>
#include <stdint.h>

// SymmetricTensorProduct: n=8192, MUL=128, DIM_IN=512
//   out_s[z,u] = (1/16)*xs[z,u]*S[z,u] + (1/(16*sqrt3))*sum_i V_i[z,u]*xv[z,u,i]
//   t[z,v,w]   = sum_u xs[z,u]*w_sv[u,v,w]
//   out_v[z,w,i] = (1/128)*sum_v t[z,v,w]*xv[z,v,i]
//
// Round-9 outv: pure L2-streaming, no LDS/barriers in the hot loop.
// Fragment-order Wt (verified r6/r8 layout) -> each A-frag is a coalesced
// 16B/lane global load. Wave = 64z (4 n-tiles) x 16w x 64v (vg half), K=128.
// Double-buffered v-pair pipeline (A 8 frags + xv 12 uints ahead), 32 MFMA +
// 96 FMA per pair. vg-combine once at the end via LDS. XCD pinned to 1MB slab.

#define NZ 8192
#define NM (8192*128)
#define SLAB 548864   // ushorts per wc slab: 67 tiles x 8192 (64 real + 3 pad)

typedef __attribute__((ext_vector_type(8))) short bf16x8;
typedef __attribute__((ext_vector_type(4))) float f32x4;

__device__ __forceinline__ ushort f2bf(float f) {
  uint32_t u = __builtin_bit_cast(uint32_t, f);
  u += 0x7fffu + ((u >> 16) & 1u);   // RNE
  return (ushort)(u >> 16);
}

// ---------------- prep: xs_bf + xvq[i][z][v] + w casts ----------------------
__global__ __launch_bounds__(256) void prep_cast(
    const float* __restrict__ x, const float* __restrict__ w_ss,
    const float* __restrict__ w_vv, ushort* __restrict__ xs_bf,
    ushort* __restrict__ xvq, ushort* __restrict__ wssb,
    ushort* __restrict__ wvvb) {
  int bid = blockIdx.x, tid = threadIdx.x;
  if (bid < 256) {
    __shared__ ushort tile[3 * 32 * 128];   // [i][zloc][v]
    int z0 = bid * 32;
#pragma unroll
    for (int it = 0; it < 16; ++it) {
      int idx = it * 256 + tid;             // 0..4095
      int zloc = idx >> 7, c4 = idx & 127;
      float4 f = *(const float4*)(x + (size_t)(z0 + zloc) * 512 + c4 * 4);
      if (c4 < 32) {
        ushort4 o;
        o.x = f2bf(f.x); o.y = f2bf(f.y); o.z = f2bf(f.z); o.w = f2bf(f.w);
        *(ushort4*)(xs_bf + (size_t)(z0 + zloc) * 128 + c4 * 4) = o;
      } else {
        int c = c4 * 4 - 128;               // 0..383
        float vals[4] = {f.x, f.y, f.z, f.w};
#pragma unroll
        for (int e = 0; e < 4; ++e) {
          int cc = c + e, v = cc / 3, i = cc - 3 * v;
          tile[i * 4096 + zloc * 128 + v] = f2bf(vals[e]);
        }
      }
    }
    __syncthreads();
#pragma unroll
    for (int it = 0; it < 6; ++it) {
      int idx = it * 256 + tid;             // 0..1535
      int i = idx >> 9, r = idx & 511;
      int zloc = r >> 4, oct = r & 15;
      *(bf16x8*)(xvq + ((size_t)i * NZ + z0 + zloc) * 128 + oct * 8) =
          *(const bf16x8*)(tile + i * 4096 + zloc * 128 + oct * 8);
    }
  } else {
    int k = (bid - 256) * 256 + tid;
    if (k < 16384) wssb[k] = f2bf(w_ss[k]);
    else wvvb[k - 16384] = f2bf(w_vv[k - 16384]);
  }
}

// ---- prep: w_sv[u][v][w] -> Wt [wc][v][wg][kk][l][e] (padded slabs) --------
__global__ __launch_bounds__(256) void prep_wt(const float* __restrict__ w_sv,
                                               ushort* __restrict__ Wt) {
  __shared__ ushort tile[4096];
  int v = blockIdx.x >> 2, wc = blockIdx.x & 3;
  int t = threadIdx.x;
  int u = t >> 1, wh = t & 1;
  const float* src = w_sv + (size_t)u * 16384 + v * 128 + wc * 32 + wh * 16;
  int kk = u >> 5, lg = (u >> 3) & 3, e = u & 7;
#pragma unroll
  for (int ww = 0; ww < 16; ++ww)
    tile[wh * 2048 + kk * 512 + (lg * 16 + ww) * 8 + e] = f2bf(src[ww]);
  __syncthreads();
  bf16x8* dst = (bf16x8*)(Wt + (size_t)wc * SLAB + (size_t)v * 4096);
  const bf16x8* s = (const bf16x8*)tile;
  dst[t] = s[t];
  dst[t + 256] = s[t + 256];
}

// ---------------- out_s via MFMA (u-half split, grid 1024) ------------------
__global__ __launch_bounds__(128) void outs_mfma(
    const float* __restrict__ x, const ushort* __restrict__ xs_bf,
    const ushort* __restrict__ wssb, const ushort* __restrict__ wvvb,
    float* __restrict__ out) {
  int bid = blockIdx.x;
  int uh = bid & 3, zb = bid >> 2;
  int tid = threadIdx.x, wid = tid >> 6, l = tid & 63;
  int lr = l & 15, lg = l >> 4;
  int z = zb * 32 + wid * 16 + lr;
  const float* xrow = x + (size_t)z * 512;

  bf16x8 bs[4], b0[4], b1[4], b2[4];
#pragma unroll
  for (int kk = 0; kk < 4; ++kk) {
    int k0 = kk * 32 + lg * 8;
    bs[kk] = *(const bf16x8*)(xs_bf + (size_t)z * 128 + k0);
    float4 f[6];
    const float4* src = (const float4*)(xrow + 128 + 3 * k0);
#pragma unroll
    for (int q = 0; q < 6; ++q) f[q] = src[q];
    const float* ff = (const float*)f;
#pragma unroll
    for (int jj = 0; jj < 8; ++jj) {
      b0[kk][jj] = (short)f2bf(ff[3 * jj + 0]);
      b1[kk][jj] = (short)f2bf(ff[3 * jj + 1]);
      b2[kk][jj] = (short)f2bf(ff[3 * jj + 2]);
    }
  }
#pragma unroll
  for (int uu = 0; uu < 2; ++uu) {
    int u0 = (uh * 2 + uu) * 16;
    f32x4 css = {0.f, 0.f, 0.f, 0.f};
    f32x4 cv0 = {0.f, 0.f, 0.f, 0.f};
    f32x4 cv1 = {0.f, 0.f, 0.f, 0.f};
    f32x4 cv2 = {0.f, 0.f, 0.f, 0.f};
#pragma unroll
    for (int kk = 0; kk < 4; ++kk) {
      int k0 = kk * 32 + lg * 8;
      bf16x8 as = *(const bf16x8*)(wssb + (size_t)(u0 + lr) * 128 + k0);
      bf16x8 av = *(const bf16x8*)(wvvb + (size_t)(u0 + lr) * 128 + k0);
      css = __builtin_amdgcn_mfma_f32_16x16x32_bf16(as, bs[kk], css, 0, 0, 0);
      cv0 = __builtin_amdgcn_mfma_f32_16x16x32_bf16(av, b0[kk], cv0, 0, 0, 0);
      cv1 = __builtin_amdgcn_mfma_f32_16x16x32_bf16(av, b1[kk], cv1, 0, 0, 0);
      cv2 = __builtin_amdgcn_mfma_f32_16x16x32_bf16(av, b2[kk], cv2, 0, 0, 0);
    }
#pragma unroll
    for (int r = 0; r < 4; ++r) {
      int u = u0 + lg * 4 + r;
      float xsv = xrow[u];
      const float* xvu = xrow + 128 + 3 * u;
      out[(size_t)z * 512 + u] =
          0.0625f * xsv * css[r] +
          0.036084391824351615f * (cv0[r] * xvu[0] + cv1[r] * xvu[1] + cv2[r] * xvu[2]);
    }
  }
}

// ---------------- out_v: L2-streaming ---------------------------------------
// grid 512 = 128 zb(64z) x 4 wc(32w); block 256 = 4 waves = 2 wg x 2 vg.
// Wave: 64z (4 n-tiles) x 16w x 64v. Per v-pair: 8 A-frag global loads +
// 12 xv uints prefetched one pair ahead; 32 MFMA + 96 FMA. No loop barriers.

#define LOADP(P_, AA, XA)                                                      \
  do {                                                                         \
    _Pragma("unroll")                                                          \
    for (int vv = 0; vv < 2; ++vv)                                             \
      _Pragma("unroll")                                                        \
      for (int kk = 0; kk < 4; ++kk)                                           \
        AA[vv * 4 + kk] =                                                      \
            *(const bf16x8*)(Ap + ((size_t)(2 * (P_) + vv)) * 4096 + kk * 512);\
    _Pragma("unroll")                                                          \
    for (int i = 0; i < 3; ++i)                                                \
      _Pragma("unroll")                                                        \
      for (int n = 0; n < 4; ++n)                                              \
        XA[i * 4 + n] = xq[i][n * 1024 + vb + (P_)];                           \
  } while (0)

#define COMPUTEP(AA, XA)                                                       \
  do {                                                                         \
    _Pragma("unroll")                                                          \
    for (int vv = 0; vv < 2; ++vv) {                                           \
      _Pragma("unroll")                                                        \
      for (int n = 0; n < 4; ++n) {                                            \
        f32x4 tt = {0.f, 0.f, 0.f, 0.f};                                       \
        __builtin_amdgcn_s_setprio(1);                                         \
        tt = __builtin_amdgcn_mfma_f32_16x16x32_bf16(AA[vv*4+0], b[n][0], tt, 0, 0, 0); \
        tt = __builtin_amdgcn_mfma_f32_16x16x32_bf16(AA[vv*4+1], b[n][1], tt, 0, 0, 0); \
        tt = __builtin_amdgcn_mfma_f32_16x16x32_bf16(AA[vv*4+2], b[n][2], tt, 0, 0, 0); \
        tt = __builtin_amdgcn_mfma_f32_16x16x32_bf16(AA[vv*4+3], b[n][3], tt, 0, 0, 0); \
        __builtin_amdgcn_s_setprio(0);                                         \
        float x0, x1, x2;                                                      \
        if (vv == 0) {                                                         \
          x0 = __builtin_bit_cast(float, XA[0 * 4 + n] << 16);                 \
          x1 = __builtin_bit_cast(float, XA[1 * 4 + n] << 16);                 \
          x2 = __builtin_bit_cast(float, XA[2 * 4 + n] << 16);                 \
        } else {                                                               \
          x0 = __builtin_bit_cast(float, XA[0 * 4 + n] & 0xffff0000u);         \
          x1 = __builtin_bit_cast(float, XA[1 * 4 + n] & 0xffff0000u);         \
          x2 = __builtin_bit_cast(float, XA[2 * 4 + n] & 0xffff0000u);         \
        }                                                                      \
        _Pragma("unroll")                                                      \
        for (int r = 0; r < 4; ++r) {                                          \
          acc[n][r][0] += tt[r] * x0;                                          \
          acc[n][r][1] += tt[r] * x1;                                          \
          acc[n][r][2] += tt[r] * x2;                                          \
        }                                                                      \
      }                                                                        \
    }                                                                          \
  } while (0)

__global__ __launch_bounds__(256, 2) void outv_kernel(
    const ushort* __restrict__ xs_bf, const ushort* __restrict__ xvq,
    const ushort* __restrict__ Wt, float* __restrict__ out) {
  __shared__ float red[2][64][48];   // 24KB, used only in epilogue
  int bid = blockIdx.x;
  int wc = bid & 3, zb = bid >> 2;
  int tid = threadIdx.x;
  int wid = tid >> 6, l = tid & 63;
  int wg = wid & 1, vg = wid >> 1;
  int lr = l & 15, lg = l >> 4;
  int z0 = zb * 64;
  int vb = vg * 32;                  // uint (v-pair) base

  // B-fragments (xs): 4 n-tiles x 4 k-chunks, held all kernel
  bf16x8 b[4][4];
#pragma unroll
  for (int n = 0; n < 4; ++n)
#pragma unroll
    for (int kk = 0; kk < 4; ++kk)
      b[n][kk] = *(const bf16x8*)(xs_bf + (size_t)(z0 + n * 16 + lr) * 128 + kk * 32 + lg * 8);

  // A stream base (fragment-order slab) and xv uint bases (per-lane z = lr-row)
  const ushort* Ap = Wt + (size_t)wc * SLAB + (size_t)vg * 64 * 4096 + wg * 2048 + l * 8;
  const uint* xq[3];
#pragma unroll
  for (int i = 0; i < 3; ++i)
    xq[i] = (const uint*)(xvq + ((size_t)i * NZ + z0 + lr) * 128);

  float acc[4][4][3] = {};
  bf16x8 pa[8], pb[8];
  uint xa[12], xb[12];

  LOADP(0, pa, xa);
  __builtin_amdgcn_sched_barrier(0);

  for (int q = 0; q < 16; ++q) {
    LOADP(2 * q + 1, pb, xb);
    __builtin_amdgcn_sched_barrier(0);
    COMPUTEP(pa, xa);
    __builtin_amdgcn_sched_barrier(0);
    LOADP(2 * q + 2, pa, xa);        // q=15 prefetches pad tile (discarded)
    __builtin_amdgcn_sched_barrier(0);
    COMPUTEP(pb, xb);
    __builtin_amdgcn_sched_barrier(0);
  }

  // vg combine via LDS, then vg=0 scales + stores
  if (vg == 1) {
#pragma unroll
    for (int n = 0; n < 4; ++n)
#pragma unroll
      for (int r = 0; r < 4; ++r)
#pragma unroll
        for (int i = 0; i < 3; ++i)
          red[wg][l][(n * 4 + r) * 3 + i] = acc[n][r][i];
  }
  __syncthreads();
  if (vg == 0) {
#pragma unroll
    for (int n = 0; n < 4; ++n) {
#pragma unroll
      for (int r = 0; r < 4; ++r) {
        int z = z0 + n * 16 + lr;
        int w = wc * 32 + wg * 16 + lg * 4 + r;
        float* o = out + (size_t)z * 512 + 128 + 3 * w;
        o[0] = (acc[n][r][0] + red[wg][l][(n * 4 + r) * 3 + 0]) * 0.0078125f;
        o[1] = (acc[n][r][1] + red[wg][l][(n * 4 + r) * 3 + 1]) * 0.0078125f;
        o[2] = (acc[n][r][2] + red[wg][l][(n * 4 + r) * 3 + 2]) * 0.0078125f;
      }
    }
  }
}

// ---------------- launch ----------------------------------------------------
extern "C" void kernel_launch(void* const* d_in, const int* in_sizes, int n_in,
                              void* d_out, int out_size, void* d_ws, size_t ws_size,
                              hipStream_t stream) {
  const float* x    = (const float*)d_in[0];
  const float* w_ss = (const float*)d_in[1];
  const float* w_sv = (const float*)d_in[2];
  const float* w_vv = (const float*)d_in[3];
  float* out = (float*)d_out;

  char* ws = (char*)d_ws;
  ushort* xs_bf = (ushort*)ws;                                  // 2 MB
  ushort* Wt    = (ushort*)(ws + (size_t)2 * 1024 * 1024);      // 4.19 MB (padded)
  ushort* xvq   = (ushort*)(ws + (size_t)6656 * 1024);          // 6 MB @ 6.5MB
  ushort* wssb  = (ushort*)(ws + (size_t)12800 * 1024);         // 32 KB @ 12.5MB
  ushort* wvvb  = (ushort*)(ws + (size_t)12800 * 1024 + 32768);

  prep_cast<<<384, 256, 0, stream>>>(x, w_ss, w_vv, xs_bf, xvq, wssb, wvvb);
  prep_wt<<<512, 256, 0, stream>>>(w_sv, Wt);
  outs_mfma<<<1024, 128, 0, stream>>>(x, xs_bf, wssb, wvvb, out);
  outv_kernel<<<512, 256, 0, stream>>>(xs_bf, xvq, Wt, out);
}

// Round 11
// 103.631 us; speedup vs baseline: 1.7175x; 1.7175x over previous
//
#include <hip/hip_runtime.h>
#include <hip/hip_bf16.h>
#include <stdint.h>

// SymmetricTensorProduct: n=8192, MUL=128, DIM_IN=512
//   out_s[z,u] = (1/16)*xs[z,u]*S[z,u] + (1/(16*sqrt3))*sum_i V_i[z,u]*xv[z,u,i]
//   t[z,v,w]   = sum_u xs[z,u]*w_sv[u,v,w]
//   out_v[z,w,i] = (1/128)*sum_v t[z,v,w]*xv[z,v,i]
//
// Round-11 = Round-10 with the staging-source bug fixed: gload16 staging uses
// the wave-UNIFORM slab base (slabS); slot halves hold tiles {T, T+64}; vg
// only selects which half a wave READS (vg*8192) and which xv it loads.
// Grid 512 = 128 zb(64z) x 4 wc(32w); 8 waves = 2 zg(32z,n=2) x 2 wg(16w)
// x 2 vg; phase = 1v/vg (64 phases), 4-slot x 16KB rotation, vmcnt(10).

#define NZ 8192
#define SLAB 548864   // ushorts per wc slab (128 tiles x 4096 used)

typedef __attribute__((ext_vector_type(8))) short bf16x8;
typedef __attribute__((ext_vector_type(4))) float f32x4;

__device__ __forceinline__ ushort f2bf(float f) {
  uint32_t u = __builtin_bit_cast(uint32_t, f);
  u += 0x7fffu + ((u >> 16) & 1u);   // RNE
  return (ushort)(u >> 16);
}
__device__ __forceinline__ float bf2f(ushort u) {
  uint32_t v = ((uint32_t)u) << 16;
  return __builtin_bit_cast(float, v);
}
__device__ __forceinline__ void gload16(const void* g, void* l) {
  __builtin_amdgcn_global_load_lds((const __attribute__((address_space(1))) void*)g,
                                   (__attribute__((address_space(3))) void*)l, 16, 0, 0);
}

// ---------------- prep: xs_bf + xvt[i][v][z] + w casts ----------------------
__global__ __launch_bounds__(256) void prep_cast(
    const float* __restrict__ x, const float* __restrict__ w_ss,
    const float* __restrict__ w_vv, ushort* __restrict__ xs_bf,
    ushort* __restrict__ xvt, ushort* __restrict__ wssb,
    ushort* __restrict__ wvvb) {
  int bid = blockIdx.x, tid = threadIdx.x;
  if (bid < 256) {
    __shared__ ushort tile[3 * 128 * 32];   // [i][v][zloc]
    int z0 = bid * 32;
#pragma unroll
    for (int it = 0; it < 16; ++it) {
      int idx = it * 256 + tid;             // 0..4095
      int zloc = idx >> 7, c4 = idx & 127;
      float4 f = *(const float4*)(x + (size_t)(z0 + zloc) * 512 + c4 * 4);
      if (c4 < 32) {
        ushort4 o;
        o.x = f2bf(f.x); o.y = f2bf(f.y); o.z = f2bf(f.z); o.w = f2bf(f.w);
        *(ushort4*)(xs_bf + (size_t)(z0 + zloc) * 128 + c4 * 4) = o;
      } else {
        int c = c4 * 4 - 128;               // 0..383
        float vals[4] = {f.x, f.y, f.z, f.w};
#pragma unroll
        for (int e = 0; e < 4; ++e) {
          int cc = c + e, v = cc / 3, i = cc - 3 * v;
          tile[i * 4096 + v * 32 + zloc] = f2bf(vals[e]);
        }
      }
    }
    __syncthreads();
#pragma unroll
    for (int it = 0; it < 6; ++it) {
      int j = it * 256 + tid;               // 0..1535 vec8s
      int row = j >> 2, part = j & 3;       // row: i*128+v
      int i = row >> 7, v = row & 127;
      *(bf16x8*)(xvt + ((size_t)i * 128 + v) * 8192 + z0 + part * 8) =
          *(const bf16x8*)(tile + i * 4096 + v * 32 + part * 8);
    }
  } else {
    int k = (bid - 256) * 256 + tid;
    if (k < 16384) wssb[k] = f2bf(w_ss[k]);
    else wvvb[k - 16384] = f2bf(w_vv[k - 16384]);
  }
}

// ---- prep: w_sv[u][v][w] -> Wt [wc][v][frag-tile 4096] ---------------------
__global__ __launch_bounds__(256) void prep_wt(const float* __restrict__ w_sv,
                                               ushort* __restrict__ Wt) {
  __shared__ ushort tile[4096];
  int v = blockIdx.x >> 2, wc = blockIdx.x & 3;
  int t = threadIdx.x;
  int u = t >> 1, wh = t & 1;
  const float* src = w_sv + (size_t)u * 16384 + v * 128 + wc * 32 + wh * 16;
  int kk = u >> 5, lg = (u >> 3) & 3, e = u & 7;
#pragma unroll
  for (int ww = 0; ww < 16; ++ww)
    tile[wh * 2048 + kk * 512 + (lg * 16 + ww) * 8 + e] = f2bf(src[ww]);
  __syncthreads();
  bf16x8* dst = (bf16x8*)(Wt + (size_t)wc * SLAB + (size_t)v * 4096);
  const bf16x8* s = (const bf16x8*)tile;
  dst[t] = s[t];
  dst[t + 256] = s[t + 256];
}

// ---------------- out_s via MFMA (u-half split, grid 1024) ------------------
__global__ __launch_bounds__(128) void outs_mfma(
    const float* __restrict__ x, const ushort* __restrict__ xs_bf,
    const ushort* __restrict__ wssb, const ushort* __restrict__ wvvb,
    float* __restrict__ out) {
  int bid = blockIdx.x;
  int uh = bid & 3, zb = bid >> 2;
  int tid = threadIdx.x, wid = tid >> 6, l = tid & 63;
  int lr = l & 15, lg = l >> 4;
  int z = zb * 32 + wid * 16 + lr;
  const float* xrow = x + (size_t)z * 512;

  bf16x8 bs[4], b0[4], b1[4], b2[4];
#pragma unroll
  for (int kk = 0; kk < 4; ++kk) {
    int k0 = kk * 32 + lg * 8;
    bs[kk] = *(const bf16x8*)(xs_bf + (size_t)z * 128 + k0);
    float4 f[6];
    const float4* src = (const float4*)(xrow + 128 + 3 * k0);
#pragma unroll
    for (int q = 0; q < 6; ++q) f[q] = src[q];
    const float* ff = (const float*)f;
#pragma unroll
    for (int jj = 0; jj < 8; ++jj) {
      b0[kk][jj] = (short)f2bf(ff[3 * jj + 0]);
      b1[kk][jj] = (short)f2bf(ff[3 * jj + 1]);
      b2[kk][jj] = (short)f2bf(ff[3 * jj + 2]);
    }
  }
#pragma unroll
  for (int uu = 0; uu < 2; ++uu) {
    int u0 = (uh * 2 + uu) * 16;
    f32x4 css = {0.f, 0.f, 0.f, 0.f};
    f32x4 cv0 = {0.f, 0.f, 0.f, 0.f};
    f32x4 cv1 = {0.f, 0.f, 0.f, 0.f};
    f32x4 cv2 = {0.f, 0.f, 0.f, 0.f};
#pragma unroll
    for (int kk = 0; kk < 4; ++kk) {
      int k0 = kk * 32 + lg * 8;
      bf16x8 as = *(const bf16x8*)(wssb + (size_t)(u0 + lr) * 128 + k0);
      bf16x8 av = *(const bf16x8*)(wvvb + (size_t)(u0 + lr) * 128 + k0);
      css = __builtin_amdgcn_mfma_f32_16x16x32_bf16(as, bs[kk], css, 0, 0, 0);
      cv0 = __builtin_amdgcn_mfma_f32_16x16x32_bf16(av, b0[kk], cv0, 0, 0, 0);
      cv1 = __builtin_amdgcn_mfma_f32_16x16x32_bf16(av, b1[kk], cv1, 0, 0, 0);
      cv2 = __builtin_amdgcn_mfma_f32_16x16x32_bf16(av, b2[kk], cv2, 0, 0, 0);
    }
#pragma unroll
    for (int r = 0; r < 4; ++r) {
      int u = u0 + lg * 4 + r;
      float xsv = xrow[u];
      const float* xvu = xrow + 128 + 3 * u;
      out[(size_t)z * 512 + u] =
          0.0625f * xsv * css[r] +
          0.036084391824351615f * (cv0[r] * xvu[0] + cv1[r] * xvu[1] + cv2[r] * xvu[2]);
    }
  }
}

// ---------------- out_v -----------------------------------------------------
// Per phase T (steady): wait vmcnt(10); barrier; load xv set for T+2 (6 ushort,
// coalesced from xvt, vg-specific); stage A tile-pair {T+3, T+67} from the
// wave-UNIFORM slabS (2 gload16); 4 ds_read_b128; 2 n-tiles x 4 MFMA; 24 FMA.

#define OUTV_PHASE(T_, CUR, STG, XC, XN)                                       \
  do {                                                                         \
    asm volatile("s_waitcnt vmcnt(10)" ::: "memory");                          \
    __builtin_amdgcn_s_barrier();                                              \
    __builtin_amdgcn_sched_barrier(0);                                         \
    {                                                                          \
      const int tv = ((T_) + 2 > 63) ? 63 : (T_) + 2;                          \
      _Pragma("unroll")                                                        \
      for (int i2 = 0; i2 < 3; ++i2)                                           \
        _Pragma("unroll")                                                      \
        for (int n2 = 0; n2 < 2; ++n2)                                         \
          XN[i2 * 2 + n2] =                                                    \
              xvt[((size_t)i2 * 128 + vbase + tv) * 8192 + zbase + n2 * 16];   \
      const int ts = ((T_) + 3 > 63) ? 63 : (T_) + 3;                          \
      const ushort* sp = slabS + (size_t)ts * 4096 + tid * 8;                  \
      gload16(sp,             lds + (STG) * 16384 + tid * 16);                 \
      gload16(sp + 64 * 4096, lds + (STG) * 16384 + 8192 + tid * 16);          \
    }                                                                          \
    __builtin_amdgcn_sched_barrier(0);                                         \
    const char* ab = lds + (CUR) * 16384 + vg * 8192 + wg * 4096 + l * 16;     \
    bf16x8 a0 = *(const bf16x8*)(ab);                                          \
    bf16x8 a1 = *(const bf16x8*)(ab + 1024);                                   \
    bf16x8 a2 = *(const bf16x8*)(ab + 2048);                                   \
    bf16x8 a3 = *(const bf16x8*)(ab + 3072);                                   \
    _Pragma("unroll")                                                          \
    for (int n = 0; n < 2; ++n) {                                              \
      f32x4 tt = {0.f, 0.f, 0.f, 0.f};                                         \
      __builtin_amdgcn_s_setprio(1);                                           \
      tt = __builtin_amdgcn_mfma_f32_16x16x32_bf16(a0, b[n][0], tt, 0, 0, 0);  \
      tt = __builtin_amdgcn_mfma_f32_16x16x32_bf16(a1, b[n][1], tt, 0, 0, 0);  \
      tt = __builtin_amdgcn_mfma_f32_16x16x32_bf16(a2, b[n][2], tt, 0, 0, 0);  \
      tt = __builtin_amdgcn_mfma_f32_16x16x32_bf16(a3, b[n][3], tt, 0, 0, 0);  \
      __builtin_amdgcn_s_setprio(0);                                           \
      float x0 = bf2f(XC[0 * 2 + n]);                                          \
      float x1 = bf2f(XC[1 * 2 + n]);                                          \
      float x2 = bf2f(XC[2 * 2 + n]);                                          \
      _Pragma("unroll")                                                        \
      for (int r = 0; r < 4; ++r) {                                            \
        acc[n][r][0] += tt[r] * x0;                                            \
        acc[n][r][1] += tt[r] * x1;                                            \
        acc[n][r][2] += tt[r] * x2;                                            \
      }                                                                        \
    }                                                                          \
  } while (0)

__global__ __launch_bounds__(512, 2) void outv_kernel(
    const ushort* __restrict__ xs_bf, const ushort* __restrict__ xvt,
    const ushort* __restrict__ Wt, float* __restrict__ out) {
  __shared__ char lds[65536];        // 4 slots x 16KB; epilogue reuses as float
  int bid = blockIdx.x;
  int wc = bid & 3, zb = bid >> 2;
  int tid = threadIdx.x;
  int wid = tid >> 6, l = tid & 63;
  int vg = wid & 1, wg = (wid >> 1) & 1, zg = (wid >> 2) & 1;
  int lr = l & 15, lg = l >> 4;
  int zbase = zb * 64 + zg * 32 + lr;   // n-tile adds 16
  int w0 = wc * 32 + wg * 16;
  int vbase = vg * 64;

  const ushort* slabS = Wt + (size_t)wc * SLAB;   // wave-uniform staging base

  // B-fragments (xs): 2 n-tiles x 4 k-chunks, held all kernel
  bf16x8 b[2][4];
#pragma unroll
  for (int n = 0; n < 2; ++n)
#pragma unroll
    for (int kk = 0; kk < 4; ++kk)
      b[n][kk] = *(const bf16x8*)(xs_bf + (size_t)(zbase + n * 16) * 128 + kk * 32 + lg * 8);
  __builtin_amdgcn_sched_barrier(0);

  ushort xa[6], xb2[6], xc[6], xd[6];
  // prologue: A0, xv0, A1, xv1, A2  (pending 18 -> vmcnt(10) completes A0+xv0)
  {
    gload16(slabS + tid * 8,             lds + tid * 16);
    gload16(slabS + 64 * 4096 + tid * 8, lds + 8192 + tid * 16);
#pragma unroll
    for (int i2 = 0; i2 < 3; ++i2)
#pragma unroll
      for (int n2 = 0; n2 < 2; ++n2)
        xa[i2 * 2 + n2] = xvt[((size_t)i2 * 128 + vbase + 0) * 8192 + zbase + n2 * 16];
    __builtin_amdgcn_sched_barrier(0);
    gload16(slabS + (size_t)1 * 4096 + tid * 8,  lds + 16384 + tid * 16);
    gload16(slabS + (size_t)65 * 4096 + tid * 8, lds + 16384 + 8192 + tid * 16);
#pragma unroll
    for (int i2 = 0; i2 < 3; ++i2)
#pragma unroll
      for (int n2 = 0; n2 < 2; ++n2)
        xb2[i2 * 2 + n2] = xvt[((size_t)i2 * 128 + vbase + 1) * 8192 + zbase + n2 * 16];
    __builtin_amdgcn_sched_barrier(0);
    gload16(slabS + (size_t)2 * 4096 + tid * 8,  lds + 32768 + tid * 16);
    gload16(slabS + (size_t)66 * 4096 + tid * 8, lds + 32768 + 8192 + tid * 16);
    __builtin_amdgcn_sched_barrier(0);
  }

  float acc[2][4][3] = {};

  for (int q = 0; q < 16; ++q) {
    OUTV_PHASE(4 * q + 0, 0, 3, xa,  xc);
    OUTV_PHASE(4 * q + 1, 1, 0, xb2, xd);
    OUTV_PHASE(4 * q + 2, 2, 1, xc,  xa);
    OUTV_PHASE(4 * q + 3, 3, 2, xd,  xb2);
  }

  // vg combine: vg1 -> LDS (pitch 25 floats), vg0 adds+stores
  __syncthreads();                    // drains tail gload_lds before LDS reuse
  float* red = (float*)lds;
  int rrow = ((zg * 2 + wg) * 64 + l) * 25;
  if (vg == 1) {
#pragma unroll
    for (int n = 0; n < 2; ++n)
#pragma unroll
      for (int r = 0; r < 4; ++r)
#pragma unroll
        for (int i = 0; i < 3; ++i)
          red[rrow + (n * 4 + r) * 3 + i] = acc[n][r][i];
  }
  __syncthreads();
  if (vg == 0) {
#pragma unroll
    for (int n = 0; n < 2; ++n) {
#pragma unroll
      for (int r = 0; r < 4; ++r) {
        int z = zbase + n * 16;
        int w = w0 + lg * 4 + r;
        float* o = out + (size_t)z * 512 + 128 + 3 * w;
        o[0] = (acc[n][r][0] + red[rrow + (n * 4 + r) * 3 + 0]) * 0.0078125f;
        o[1] = (acc[n][r][1] + red[rrow + (n * 4 + r) * 3 + 1]) * 0.0078125f;
        o[2] = (acc[n][r][2] + red[rrow + (n * 4 + r) * 3 + 2]) * 0.0078125f;
      }
    }
  }
}

// ---------------- launch ----------------------------------------------------
extern "C" void kernel_launch(void* const* d_in, const int* in_sizes, int n_in,
                              void* d_out, int out_size, void* d_ws, size_t ws_size,
                              hipStream_t stream) {
  const float* x    = (const float*)d_in[0];
  const float* w_ss = (const float*)d_in[1];
  const float* w_sv = (const float*)d_in[2];
  const float* w_vv = (const float*)d_in[3];
  float* out = (float*)d_out;

  char* ws = (char*)d_ws;
  ushort* xs_bf = (ushort*)ws;                                  // 2 MB
  ushort* Wt    = (ushort*)(ws + (size_t)2 * 1024 * 1024);      // 4.19 MB
  ushort* xvt   = (ushort*)(ws + (size_t)6656 * 1024);          // 6 MB @ 6.5MB
  ushort* wssb  = (ushort*)(ws + (size_t)12800 * 1024);         // 32 KB @ 12.5MB
  ushort* wvvb  = (ushort*)(ws + (size_t)12800 * 1024 + 32768);

  prep_cast<<<384, 256, 0, stream>>>(x, w_ss, w_vv, xs_bf, xvt, wssb, wvvb);
  prep_wt<<<512, 256, 0, stream>>>(w_sv, Wt);
  outs_mfma<<<1024, 128, 0, stream>>>(x, xs_bf, wssb, wvvb, out);
  outv_kernel<<<512, 512, 0, stream>>>(xs_bf, xvt, Wt, out);
}

// Round 12
// 95.482 us; speedup vs baseline: 1.8640x; 1.0853x over previous
//
#include <hip/hip_runtime.h>
#include <hip/hip_bf16.h>
#include <stdint.h>

// SymmetricTensorProduct: n=8192, MUL=128, DIM_IN=512
//   out_s[z,u] = (1/16)*xs[z,u]*S[z,u] + (1/(16*sqrt3))*sum_i V_i[z,u]*xv[z,u,i]
//   t[z,v,w]   = sum_u xs[z,u]*w_sv[u,v,w]
//   out_v[z,w,i] = (1/128)*sum_v t[z,v,w]*xv[z,v,i]
//
// Round-12 outv: barrier-free global-stream (r9 skeleton, proven correct)
// inside the 128-VGPR no-spill envelope (n=2). No LDS, no s_barrier, no vg.
// Grid 256 = 64 zb(128z) x 4 wc(32w), 1 block/CU, XCD-pinned 1MB slab.
// 8 waves = 4 zg(32z) x 2 wg(16w); wave streams all 128 v, depth-1 software
// pipeline (pa/pb + xa/xb). The 4 zg waves read identical A addresses -> L1
// shares the stream (block A-traffic 1MB, chip 256MB L2).

#define NZ 8192
#define SLAB 548864   // ushorts per wc slab (128 tiles x 4096 used + pad)

typedef __attribute__((ext_vector_type(8))) short bf16x8;
typedef __attribute__((ext_vector_type(4))) float f32x4;

__device__ __forceinline__ ushort f2bf(float f) {
  uint32_t u = __builtin_bit_cast(uint32_t, f);
  u += 0x7fffu + ((u >> 16) & 1u);   // RNE
  return (ushort)(u >> 16);
}
__device__ __forceinline__ float bf2f(ushort u) {
  uint32_t v = ((uint32_t)u) << 16;
  return __builtin_bit_cast(float, v);
}

// ---------------- prep: xs_bf + xvt[i][v][z] + w casts ----------------------
__global__ __launch_bounds__(256) void prep_cast(
    const float* __restrict__ x, const float* __restrict__ w_ss,
    const float* __restrict__ w_vv, ushort* __restrict__ xs_bf,
    ushort* __restrict__ xvt, ushort* __restrict__ wssb,
    ushort* __restrict__ wvvb) {
  int bid = blockIdx.x, tid = threadIdx.x;
  if (bid < 256) {
    __shared__ ushort tile[3 * 128 * 32];   // [i][v][zloc]
    int z0 = bid * 32;
#pragma unroll
    for (int it = 0; it < 16; ++it) {
      int idx = it * 256 + tid;             // 0..4095
      int zloc = idx >> 7, c4 = idx & 127;
      float4 f = *(const float4*)(x + (size_t)(z0 + zloc) * 512 + c4 * 4);
      if (c4 < 32) {
        ushort4 o;
        o.x = f2bf(f.x); o.y = f2bf(f.y); o.z = f2bf(f.z); o.w = f2bf(f.w);
        *(ushort4*)(xs_bf + (size_t)(z0 + zloc) * 128 + c4 * 4) = o;
      } else {
        int c = c4 * 4 - 128;               // 0..383
        float vals[4] = {f.x, f.y, f.z, f.w};
#pragma unroll
        for (int e = 0; e < 4; ++e) {
          int cc = c + e, v = cc / 3, i = cc - 3 * v;
          tile[i * 4096 + v * 32 + zloc] = f2bf(vals[e]);
        }
      }
    }
    __syncthreads();
#pragma unroll
    for (int it = 0; it < 6; ++it) {
      int j = it * 256 + tid;               // 0..1535 vec8s
      int row = j >> 2, part = j & 3;       // row: i*128+v
      int i = row >> 7, v = row & 127;
      *(bf16x8*)(xvt + ((size_t)i * 128 + v) * 8192 + z0 + part * 8) =
          *(const bf16x8*)(tile + i * 4096 + v * 32 + part * 8);
    }
  } else {
    int k = (bid - 256) * 256 + tid;
    if (k < 16384) wssb[k] = f2bf(w_ss[k]);
    else wvvb[k - 16384] = f2bf(w_vv[k - 16384]);
  }
}

// ---- prep: w_sv[u][v][w] -> Wt [wc][v][wg][kk][l][e] (padded slabs) --------
__global__ __launch_bounds__(256) void prep_wt(const float* __restrict__ w_sv,
                                               ushort* __restrict__ Wt) {
  __shared__ ushort tile[4096];
  int v = blockIdx.x >> 2, wc = blockIdx.x & 3;
  int t = threadIdx.x;
  int u = t >> 1, wh = t & 1;
  const float* src = w_sv + (size_t)u * 16384 + v * 128 + wc * 32 + wh * 16;
  int kk = u >> 5, lg = (u >> 3) & 3, e = u & 7;
#pragma unroll
  for (int ww = 0; ww < 16; ++ww)
    tile[wh * 2048 + kk * 512 + (lg * 16 + ww) * 8 + e] = f2bf(src[ww]);
  __syncthreads();
  bf16x8* dst = (bf16x8*)(Wt + (size_t)wc * SLAB + (size_t)v * 4096);
  const bf16x8* s = (const bf16x8*)tile;
  dst[t] = s[t];
  dst[t + 256] = s[t + 256];
}

// ---------------- out_s via MFMA (u-half split, grid 1024) ------------------
__global__ __launch_bounds__(128) void outs_mfma(
    const float* __restrict__ x, const ushort* __restrict__ xs_bf,
    const ushort* __restrict__ wssb, const ushort* __restrict__ wvvb,
    float* __restrict__ out) {
  int bid = blockIdx.x;
  int uh = bid & 3, zb = bid >> 2;
  int tid = threadIdx.x, wid = tid >> 6, l = tid & 63;
  int lr = l & 15, lg = l >> 4;
  int z = zb * 32 + wid * 16 + lr;
  const float* xrow = x + (size_t)z * 512;

  bf16x8 bs[4], b0[4], b1[4], b2[4];
#pragma unroll
  for (int kk = 0; kk < 4; ++kk) {
    int k0 = kk * 32 + lg * 8;
    bs[kk] = *(const bf16x8*)(xs_bf + (size_t)z * 128 + k0);
    float4 f[6];
    const float4* src = (const float4*)(xrow + 128 + 3 * k0);
#pragma unroll
    for (int q = 0; q < 6; ++q) f[q] = src[q];
    const float* ff = (const float*)f;
#pragma unroll
    for (int jj = 0; jj < 8; ++jj) {
      b0[kk][jj] = (short)f2bf(ff[3 * jj + 0]);
      b1[kk][jj] = (short)f2bf(ff[3 * jj + 1]);
      b2[kk][jj] = (short)f2bf(ff[3 * jj + 2]);
    }
  }
#pragma unroll
  for (int uu = 0; uu < 2; ++uu) {
    int u0 = (uh * 2 + uu) * 16;
    f32x4 css = {0.f, 0.f, 0.f, 0.f};
    f32x4 cv0 = {0.f, 0.f, 0.f, 0.f};
    f32x4 cv1 = {0.f, 0.f, 0.f, 0.f};
    f32x4 cv2 = {0.f, 0.f, 0.f, 0.f};
#pragma unroll
    for (int kk = 0; kk < 4; ++kk) {
      int k0 = kk * 32 + lg * 8;
      bf16x8 as = *(const bf16x8*)(wssb + (size_t)(u0 + lr) * 128 + k0);
      bf16x8 av = *(const bf16x8*)(wvvb + (size_t)(u0 + lr) * 128 + k0);
      css = __builtin_amdgcn_mfma_f32_16x16x32_bf16(as, bs[kk], css, 0, 0, 0);
      cv0 = __builtin_amdgcn_mfma_f32_16x16x32_bf16(av, b0[kk], cv0, 0, 0, 0);
      cv1 = __builtin_amdgcn_mfma_f32_16x16x32_bf16(av, b1[kk], cv1, 0, 0, 0);
      cv2 = __builtin_amdgcn_mfma_f32_16x16x32_bf16(av, b2[kk], cv2, 0, 0, 0);
    }
#pragma unroll
    for (int r = 0; r < 4; ++r) {
      int u = u0 + lg * 4 + r;
      float xsv = xrow[u];
      const float* xvu = xrow + 128 + 3 * u;
      out[(size_t)z * 512 + u] =
          0.0625f * xsv * css[r] +
          0.036084391824351615f * (cv0[r] * xvu[0] + cv1[r] * xvu[1] + cv2[r] * xvu[2]);
    }
  }
}

// ---------------- out_v: barrier-free global stream -------------------------
#define LOADV(V_, PA, XA)                                                      \
  do {                                                                         \
    const ushort* ap = Ap + (size_t)(V_) * 4096;                               \
    PA[0] = *(const bf16x8*)(ap);                                              \
    PA[1] = *(const bf16x8*)(ap + 512);                                        \
    PA[2] = *(const bf16x8*)(ap + 1024);                                       \
    PA[3] = *(const bf16x8*)(ap + 1536);                                       \
    XA[0] = xq0[(size_t)(V_) * 8192];                                          \
    XA[1] = xq0[(size_t)(V_) * 8192 + 16];                                     \
    XA[2] = xq1[(size_t)(V_) * 8192];                                          \
    XA[3] = xq1[(size_t)(V_) * 8192 + 16];                                     \
    XA[4] = xq2[(size_t)(V_) * 8192];                                          \
    XA[5] = xq2[(size_t)(V_) * 8192 + 16];                                     \
  } while (0)

#define COMPUTEV(PA, XA)                                                       \
  do {                                                                         \
    _Pragma("unroll")                                                          \
    for (int n = 0; n < 2; ++n) {                                              \
      f32x4 tt = {0.f, 0.f, 0.f, 0.f};                                         \
      __builtin_amdgcn_s_setprio(1);                                           \
      tt = __builtin_amdgcn_mfma_f32_16x16x32_bf16(PA[0], b[n][0], tt, 0, 0, 0);\
      tt = __builtin_amdgcn_mfma_f32_16x16x32_bf16(PA[1], b[n][1], tt, 0, 0, 0);\
      tt = __builtin_amdgcn_mfma_f32_16x16x32_bf16(PA[2], b[n][2], tt, 0, 0, 0);\
      tt = __builtin_amdgcn_mfma_f32_16x16x32_bf16(PA[3], b[n][3], tt, 0, 0, 0);\
      __builtin_amdgcn_s_setprio(0);                                           \
      float x0 = bf2f(XA[0 + n]);                                              \
      float x1 = bf2f(XA[2 + n]);                                              \
      float x2 = bf2f(XA[4 + n]);                                              \
      _Pragma("unroll")                                                        \
      for (int r = 0; r < 4; ++r) {                                            \
        acc[n][r][0] += tt[r] * x0;                                            \
        acc[n][r][1] += tt[r] * x1;                                            \
        acc[n][r][2] += tt[r] * x2;                                            \
      }                                                                        \
    }                                                                          \
  } while (0)

__global__ __launch_bounds__(512, 4) void outv_kernel(
    const ushort* __restrict__ xs_bf, const ushort* __restrict__ xvt,
    const ushort* __restrict__ Wt, float* __restrict__ out) {
  int bid = blockIdx.x;
  int wc = bid & 3, zb = bid >> 2;
  int tid = threadIdx.x;
  int wid = tid >> 6, l = tid & 63;
  int wg = wid & 1, zg = wid >> 1;
  int lr = l & 15, lg = l >> 4;
  int zbase = zb * 128 + zg * 32 + lr;   // n-tile adds 16
  int w0 = wc * 32 + wg * 16;

  // per-wave A stream base: fragment-order tile [wg][kk][l][e]
  const ushort* Ap = Wt + (size_t)wc * SLAB + wg * 2048 + l * 8;
  const ushort* xq0 = xvt + ((size_t)0 * 128) * 8192 + zbase;
  const ushort* xq1 = xvt + ((size_t)1 * 128) * 8192 + zbase;
  const ushort* xq2 = xvt + ((size_t)2 * 128) * 8192 + zbase;

  // B-fragments (xs): 2 n-tiles x 4 k-chunks, held all kernel
  bf16x8 b[2][4];
#pragma unroll
  for (int n = 0; n < 2; ++n)
#pragma unroll
    for (int kk = 0; kk < 4; ++kk)
      b[n][kk] = *(const bf16x8*)(xs_bf + (size_t)(zbase + n * 16) * 128 + kk * 32 + lg * 8);

  float acc[2][4][3] = {};
  bf16x8 pa[4], pb[4];
  ushort xa[6], xb[6];

  LOADV(0, pa, xa);
  __builtin_amdgcn_sched_barrier(0);

  for (int q = 0; q < 64; ++q) {
    LOADV(2 * q + 1, pb, xb);
    __builtin_amdgcn_sched_barrier(0);
    COMPUTEV(pa, xa);
    __builtin_amdgcn_sched_barrier(0);
    LOADV(2 * q + 2, pa, xa);      // q=63 loads pad tile 128 (discarded)
    __builtin_amdgcn_sched_barrier(0);
    COMPUTEV(pb, xb);
    __builtin_amdgcn_sched_barrier(0);
  }

#pragma unroll
  for (int n = 0; n < 2; ++n) {
#pragma unroll
    for (int r = 0; r < 4; ++r) {
      int z = zbase + n * 16;
      int w = w0 + lg * 4 + r;
      float* o = out + (size_t)z * 512 + 128 + 3 * w;
      o[0] = acc[n][r][0] * 0.0078125f;
      o[1] = acc[n][r][1] * 0.0078125f;
      o[2] = acc[n][r][2] * 0.0078125f;
    }
  }
}

// ---------------- launch ----------------------------------------------------
extern "C" void kernel_launch(void* const* d_in, const int* in_sizes, int n_in,
                              void* d_out, int out_size, void* d_ws, size_t ws_size,
                              hipStream_t stream) {
  const float* x    = (const float*)d_in[0];
  const float* w_ss = (const float*)d_in[1];
  const float* w_sv = (const float*)d_in[2];
  const float* w_vv = (const float*)d_in[3];
  float* out = (float*)d_out;

  char* ws = (char*)d_ws;
  ushort* xs_bf = (ushort*)ws;                                  // 2 MB
  ushort* Wt    = (ushort*)(ws + (size_t)2 * 1024 * 1024);      // 4.19 MB
  ushort* xvt   = (ushort*)(ws + (size_t)6656 * 1024);          // 6 MB @ 6.5MB
  ushort* wssb  = (ushort*)(ws + (size_t)12800 * 1024);         // 32 KB @ 12.5MB
  ushort* wvvb  = (ushort*)(ws + (size_t)12800 * 1024 + 32768);

  prep_cast<<<384, 256, 0, stream>>>(x, w_ss, w_vv, xs_bf, xvt, wssb, wvvb);
  prep_wt<<<512, 256, 0, stream>>>(w_sv, Wt);
  outs_mfma<<<1024, 128, 0, stream>>>(x, xs_bf, wssb, wvvb, out);
  outv_kernel<<<256, 512, 0, stream>>>(xs_bf, xvt, Wt, out);
}

// Round 13
// 87.555 us; speedup vs baseline: 2.0328x; 1.0905x over previous
//
#include <hip/hip_runtime.h>
#include <hip/hip_bf16.h>
#include <stdint.h>

// SymmetricTensorProduct: n=8192, MUL=128, DIM_IN=512
//   out_s[z,u] = (1/16)*xs[z,u]*S[z,u] + (1/(16*sqrt3))*sum_i V_i[z,u]*xv[z,u,i]
//   t[z,v,w]   = sum_u xs[z,u]*w_sv[u,v,w]
//   out_v[z,w,i] = (1/128)*sum_v t[z,v,w]*xv[z,v,i]
//
// Round-13 outv: r12's barrier-free global-stream loop (proven correct,
// VGPR 64) at 2 blocks/CU via vg-split: grid 512 = 128 zb(64z) x 4 wc(32w);
// 8 waves = 2 zg(32z,n=2) x 2 wg(16w) x 2 vg(64v). vg halves combined once
// at the end via LDS (r11-verified epilogue). Preps merged into one launch.

#define NZ 8192
#define SLAB 548864   // ushorts per wc slab (128 tiles x 4096 used + pad)

typedef __attribute__((ext_vector_type(8))) short bf16x8;
typedef __attribute__((ext_vector_type(4))) float f32x4;

__device__ __forceinline__ ushort f2bf(float f) {
  uint32_t u = __builtin_bit_cast(uint32_t, f);
  u += 0x7fffu + ((u >> 16) & 1u);   // RNE
  return (ushort)(u >> 16);
}
__device__ __forceinline__ float bf2f(ushort u) {
  uint32_t v = ((uint32_t)u) << 16;
  return __builtin_bit_cast(float, v);
}

// ---------------- prep (merged): xs_bf + xvt + w casts + Wt -----------------
__global__ __launch_bounds__(256) void prep_all(
    const float* __restrict__ x, const float* __restrict__ w_ss,
    const float* __restrict__ w_vv, const float* __restrict__ w_sv,
    ushort* __restrict__ xs_bf, ushort* __restrict__ xvt,
    ushort* __restrict__ wssb, ushort* __restrict__ wvvb,
    ushort* __restrict__ Wt) {
  __shared__ ushort tile[12288];
  int bid = blockIdx.x, tid = threadIdx.x;
  if (bid < 256) {
    // x -> xs_bf[z][u] and xvt[i][v][z] (LDS transpose), 32 z per block
    int z0 = bid * 32;
#pragma unroll
    for (int it = 0; it < 16; ++it) {
      int idx = it * 256 + tid;             // 0..4095
      int zloc = idx >> 7, c4 = idx & 127;
      float4 f = *(const float4*)(x + (size_t)(z0 + zloc) * 512 + c4 * 4);
      if (c4 < 32) {
        ushort4 o;
        o.x = f2bf(f.x); o.y = f2bf(f.y); o.z = f2bf(f.z); o.w = f2bf(f.w);
        *(ushort4*)(xs_bf + (size_t)(z0 + zloc) * 128 + c4 * 4) = o;
      } else {
        int c = c4 * 4 - 128;               // 0..383
        float vals[4] = {f.x, f.y, f.z, f.w};
#pragma unroll
        for (int e = 0; e < 4; ++e) {
          int cc = c + e, v = cc / 3, i = cc - 3 * v;
          tile[i * 4096 + v * 32 + zloc] = f2bf(vals[e]);
        }
      }
    }
    __syncthreads();
#pragma unroll
    for (int it = 0; it < 6; ++it) {
      int j = it * 256 + tid;               // 0..1535 vec8s
      int row = j >> 2, part = j & 3;       // row: i*128+v
      int i = row >> 7, v = row & 127;
      *(bf16x8*)(xvt + ((size_t)i * 128 + v) * 8192 + z0 + part * 8) =
          *(const bf16x8*)(tile + i * 4096 + v * 32 + part * 8);
    }
  } else if (bid < 384) {
    int k = (bid - 256) * 256 + tid;
    if (k < 16384) wssb[k] = f2bf(w_ss[k]);
    else wvvb[k - 16384] = f2bf(w_vv[k - 16384]);
  } else {
    // w_sv[u][v][w] -> Wt [wc][v][wg][kk][l][e] fragment order
    int q = bid - 384;
    int v = q >> 2, wc = q & 3;
    int u = tid >> 1, wh = tid & 1;
    const float* src = w_sv + (size_t)u * 16384 + v * 128 + wc * 32 + wh * 16;
    int kk = u >> 5, lg = (u >> 3) & 3, e = u & 7;
#pragma unroll
    for (int ww = 0; ww < 16; ++ww)
      tile[wh * 2048 + kk * 512 + (lg * 16 + ww) * 8 + e] = f2bf(src[ww]);
    __syncthreads();
    bf16x8* dst = (bf16x8*)(Wt + (size_t)wc * SLAB + (size_t)v * 4096);
    const bf16x8* s = (const bf16x8*)tile;
    dst[tid] = s[tid];
    dst[tid + 256] = s[tid + 256];
  }
}

// ---------------- out_s via MFMA (u-half split, grid 1024) ------------------
__global__ __launch_bounds__(128) void outs_mfma(
    const float* __restrict__ x, const ushort* __restrict__ xs_bf,
    const ushort* __restrict__ wssb, const ushort* __restrict__ wvvb,
    float* __restrict__ out) {
  int bid = blockIdx.x;
  int uh = bid & 3, zb = bid >> 2;
  int tid = threadIdx.x, wid = tid >> 6, l = tid & 63;
  int lr = l & 15, lg = l >> 4;
  int z = zb * 32 + wid * 16 + lr;
  const float* xrow = x + (size_t)z * 512;

  bf16x8 bs[4], b0[4], b1[4], b2[4];
#pragma unroll
  for (int kk = 0; kk < 4; ++kk) {
    int k0 = kk * 32 + lg * 8;
    bs[kk] = *(const bf16x8*)(xs_bf + (size_t)z * 128 + k0);
    float4 f[6];
    const float4* src = (const float4*)(xrow + 128 + 3 * k0);
#pragma unroll
    for (int q = 0; q < 6; ++q) f[q] = src[q];
    const float* ff = (const float*)f;
#pragma unroll
    for (int jj = 0; jj < 8; ++jj) {
      b0[kk][jj] = (short)f2bf(ff[3 * jj + 0]);
      b1[kk][jj] = (short)f2bf(ff[3 * jj + 1]);
      b2[kk][jj] = (short)f2bf(ff[3 * jj + 2]);
    }
  }
#pragma unroll
  for (int uu = 0; uu < 2; ++uu) {
    int u0 = (uh * 2 + uu) * 16;
    f32x4 css = {0.f, 0.f, 0.f, 0.f};
    f32x4 cv0 = {0.f, 0.f, 0.f, 0.f};
    f32x4 cv1 = {0.f, 0.f, 0.f, 0.f};
    f32x4 cv2 = {0.f, 0.f, 0.f, 0.f};
#pragma unroll
    for (int kk = 0; kk < 4; ++kk) {
      int k0 = kk * 32 + lg * 8;
      bf16x8 as = *(const bf16x8*)(wssb + (size_t)(u0 + lr) * 128 + k0);
      bf16x8 av = *(const bf16x8*)(wvvb + (size_t)(u0 + lr) * 128 + k0);
      css = __builtin_amdgcn_mfma_f32_16x16x32_bf16(as, bs[kk], css, 0, 0, 0);
      cv0 = __builtin_amdgcn_mfma_f32_16x16x32_bf16(av, b0[kk], cv0, 0, 0, 0);
      cv1 = __builtin_amdgcn_mfma_f32_16x16x32_bf16(av, b1[kk], cv1, 0, 0, 0);
      cv2 = __builtin_amdgcn_mfma_f32_16x16x32_bf16(av, b2[kk], cv2, 0, 0, 0);
    }
#pragma unroll
    for (int r = 0; r < 4; ++r) {
      int u = u0 + lg * 4 + r;
      float xsv = xrow[u];
      const float* xvu = xrow + 128 + 3 * u;
      out[(size_t)z * 512 + u] =
          0.0625f * xsv * css[r] +
          0.036084391824351615f * (cv0[r] * xvu[0] + cv1[r] * xvu[1] + cv2[r] * xvu[2]);
    }
  }
}

// ---------------- out_v: barrier-free global stream, vg-split ---------------
#define LOADV(V_, PA, XA)                                                      \
  do {                                                                         \
    const ushort* ap = Ap + (size_t)(V_) * 4096;                               \
    PA[0] = *(const bf16x8*)(ap);                                              \
    PA[1] = *(const bf16x8*)(ap + 512);                                        \
    PA[2] = *(const bf16x8*)(ap + 1024);                                       \
    PA[3] = *(const bf16x8*)(ap + 1536);                                       \
    XA[0] = xq0[(size_t)(V_) * 8192];                                          \
    XA[1] = xq0[(size_t)(V_) * 8192 + 16];                                     \
    XA[2] = xq1[(size_t)(V_) * 8192];                                          \
    XA[3] = xq1[(size_t)(V_) * 8192 + 16];                                     \
    XA[4] = xq2[(size_t)(V_) * 8192];                                          \
    XA[5] = xq2[(size_t)(V_) * 8192 + 16];                                     \
  } while (0)

#define COMPUTEV(PA, XA)                                                       \
  do {                                                                         \
    _Pragma("unroll")                                                          \
    for (int n = 0; n < 2; ++n) {                                              \
      f32x4 tt = {0.f, 0.f, 0.f, 0.f};                                         \
      __builtin_amdgcn_s_setprio(1);                                           \
      tt = __builtin_amdgcn_mfma_f32_16x16x32_bf16(PA[0], b[n][0], tt, 0, 0, 0);\
      tt = __builtin_amdgcn_mfma_f32_16x16x32_bf16(PA[1], b[n][1], tt, 0, 0, 0);\
      tt = __builtin_amdgcn_mfma_f32_16x16x32_bf16(PA[2], b[n][2], tt, 0, 0, 0);\
      tt = __builtin_amdgcn_mfma_f32_16x16x32_bf16(PA[3], b[n][3], tt, 0, 0, 0);\
      __builtin_amdgcn_s_setprio(0);                                           \
      float x0 = bf2f(XA[0 + n]);                                              \
      float x1 = bf2f(XA[2 + n]);                                              \
      float x2 = bf2f(XA[4 + n]);                                              \
      _Pragma("unroll")                                                        \
      for (int r = 0; r < 4; ++r) {                                            \
        acc[n][r][0] += tt[r] * x0;                                            \
        acc[n][r][1] += tt[r] * x1;                                            \
        acc[n][r][2] += tt[r] * x2;                                            \
      }                                                                        \
    }                                                                          \
  } while (0)

__global__ __launch_bounds__(512, 4) void outv_kernel(
    const ushort* __restrict__ xs_bf, const ushort* __restrict__ xvt,
    const ushort* __restrict__ Wt, float* __restrict__ out) {
  __shared__ float red[256][25];     // 25.6KB, epilogue only
  int bid = blockIdx.x;
  int wc = bid & 3, zb = bid >> 2;
  int tid = threadIdx.x;
  int wid = tid >> 6, l = tid & 63;
  int vg = wid & 1, wg = (wid >> 1) & 1, zg = (wid >> 2) & 1;
  int lr = l & 15, lg = l >> 4;
  int zbase = zb * 64 + zg * 32 + lr;   // n-tile adds 16
  int w0 = wc * 32 + wg * 16;
  int vbase = vg * 64;

  // per-wave A stream base: fragment-order tile [wg][kk][l][e]
  const ushort* Ap = Wt + (size_t)wc * SLAB + (size_t)vbase * 4096 + wg * 2048 + l * 8;
  const ushort* xq0 = xvt + ((size_t)(0 * 128 + vbase)) * 8192 + zbase;
  const ushort* xq1 = xvt + ((size_t)(1 * 128 + vbase)) * 8192 + zbase;
  const ushort* xq2 = xvt + ((size_t)(2 * 128 + vbase)) * 8192 + zbase;

  // B-fragments (xs): 2 n-tiles x 4 k-chunks, held all kernel
  bf16x8 b[2][4];
#pragma unroll
  for (int n = 0; n < 2; ++n)
#pragma unroll
    for (int kk = 0; kk < 4; ++kk)
      b[n][kk] = *(const bf16x8*)(xs_bf + (size_t)(zbase + n * 16) * 128 + kk * 32 + lg * 8);

  float acc[2][4][3] = {};
  bf16x8 pa[4], pb[4];
  ushort xa[6], xb[6];

  LOADV(0, pa, xa);
  __builtin_amdgcn_sched_barrier(0);

  for (int q = 0; q < 32; ++q) {
    LOADV(2 * q + 1, pb, xb);
    __builtin_amdgcn_sched_barrier(0);
    COMPUTEV(pa, xa);
    __builtin_amdgcn_sched_barrier(0);
    LOADV(2 * q + 2, pa, xa);      // q=31 loads tile 64 (overrun into next vg
    __builtin_amdgcn_sched_barrier(0);  //  slab / pad region; discarded)
    COMPUTEV(pb, xb);
    __builtin_amdgcn_sched_barrier(0);
  }

  // vg combine: vg1 -> LDS, vg0 adds + stores
  int rrow = (zg * 2 + wg) * 64 + l;
  if (vg == 1) {
#pragma unroll
    for (int n = 0; n < 2; ++n)
#pragma unroll
      for (int r = 0; r < 4; ++r)
#pragma unroll
        for (int i = 0; i < 3; ++i)
          red[rrow][(n * 4 + r) * 3 + i] = acc[n][r][i];
  }
  __syncthreads();
  if (vg == 0) {
#pragma unroll
    for (int n = 0; n < 2; ++n) {
#pragma unroll
      for (int r = 0; r < 4; ++r) {
        int z = zbase + n * 16;
        int w = w0 + lg * 4 + r;
        float* o = out + (size_t)z * 512 + 128 + 3 * w;
        o[0] = (acc[n][r][0] + red[rrow][(n * 4 + r) * 3 + 0]) * 0.0078125f;
        o[1] = (acc[n][r][1] + red[rrow][(n * 4 + r) * 3 + 1]) * 0.0078125f;
        o[2] = (acc[n][r][2] + red[rrow][(n * 4 + r) * 3 + 2]) * 0.0078125f;
      }
    }
  }
}

// ---------------- launch ----------------------------------------------------
extern "C" void kernel_launch(void* const* d_in, const int* in_sizes, int n_in,
                              void* d_out, int out_size, void* d_ws, size_t ws_size,
                              hipStream_t stream) {
  const float* x    = (const float*)d_in[0];
  const float* w_ss = (const float*)d_in[1];
  const float* w_sv = (const float*)d_in[2];
  const float* w_vv = (const float*)d_in[3];
  float* out = (float*)d_out;

  char* ws = (char*)d_ws;
  ushort* xs_bf = (ushort*)ws;                                  // 2 MB
  ushort* Wt    = (ushort*)(ws + (size_t)2 * 1024 * 1024);      // 4.19 MB
  ushort* xvt   = (ushort*)(ws + (size_t)6656 * 1024);          // 6 MB @ 6.5MB
  ushort* wssb  = (ushort*)(ws + (size_t)12800 * 1024);         // 32 KB @ 12.5MB
  ushort* wvvb  = (ushort*)(ws + (size_t)12800 * 1024 + 32768);

  prep_all<<<896, 256, 0, stream>>>(x, w_ss, w_vv, w_sv,
                                    xs_bf, xvt, wssb, wvvb, Wt);
  outs_mfma<<<1024, 128, 0, stream>>>(x, xs_bf, wssb, wvvb, out);
  outv_kernel<<<512, 512, 0, stream>>>(xs_bf, xvt, Wt, out);
}